// Round 4
// baseline (177.365 us; speedup 1.0000x reference)
//
#include <hip/hip_runtime.h>
#include <hip/hip_bf16.h>

typedef unsigned short ushort_t;
typedef __attribute__((ext_vector_type(8))) short bf16x8;
typedef __attribute__((ext_vector_type(4))) float f32x4;

// Problem constants
#define NROWS 16384          // B*T
#define FDIM  512            // K
#define GE    640            // G*E
#define EDIM  320
#define DDIM  384
#define CB_OFF 12582912      // 16384*768
#define SCAL_OFF 23068672    // CB_OFF + 16384*640
// bf16 staging inside out[quantized region] (free until vq_rows)
#define XB_OFF 0             // 8388608 bf16 = 4194304 floats
#define WB_OFF 4194304       // floats; 327680 bf16 = 163840 floats

// ---------------- init accumulators ----------------
__global__ void vq_init_k(float* acc, int n) {
    int i = blockIdx.x * 256 + threadIdx.x;
    if (i < n) acc[i] = 0.0f;
}

// ---------------- fp32 -> bf16 convert (RNE) ----------------
static __device__ __forceinline__ unsigned f2bf(float f) {
    unsigned u = __float_as_uint(f);
    return (u + 0x7FFFu + ((u >> 16) & 1u)) >> 16;
}

__global__ __launch_bounds__(256) void convert_bf16_k(
    const float* __restrict__ X, const float* __restrict__ W,
    ushort_t* __restrict__ Xb, ushort_t* __restrict__ Wb)
{
    const size_t i = (size_t)blockIdx.x * 256 + threadIdx.x;
    const float4* src;
    ushort_t* dst;
    if (i < 1048576) {                    // X: 8388608 elems / 8
        src = (const float4*)X + i * 2;
        dst = Xb + i * 8;
    } else {                              // W: 327680 elems / 8
        const size_t j = i - 1048576;
        src = (const float4*)W + j * 2;
        dst = Wb + j * 8;
    }
    const float4 v0 = src[0], v1 = src[1];
    uint4 o;
    o.x = f2bf(v0.x) | (f2bf(v0.y) << 16);
    o.y = f2bf(v0.z) | (f2bf(v0.w) << 16);
    o.z = f2bf(v1.x) | (f2bf(v1.y) << 16);
    o.w = f2bf(v1.z) | (f2bf(v1.w) << 16);
    *(uint4*)dst = o;
}

// ---------------- async global->LDS helper ----------------
static __device__ __forceinline__ void gload16(const void* g, void* l) {
    __builtin_amdgcn_global_load_lds(
        (const __attribute__((address_space(1))) unsigned int*)g,
        (__attribute__((address_space(3))) unsigned int*)l, 16, 0, 0);
}

// ---------------- MFMA GEMM: L = Xb @ Wb^T + b ----------------
__global__ __launch_bounds__(256) void gemm_mfma_k(
    const ushort_t* __restrict__ Xb, const ushort_t* __restrict__ Wb,
    const float* __restrict__ bias, float* __restrict__ L)
{
    __shared__ __align__(16) ushort_t As[128 * 32];   // [row][k], 64B/row
    __shared__ __align__(16) ushort_t Bs[128 * 32];

    const int tid  = threadIdx.x;
    const int lane = tid & 63;
    const int wv   = tid >> 6;          // 0..3
    const int wr   = (wv >> 1) * 64;
    const int wc   = (wv & 1) * 64;
    const int row0 = blockIdx.x * 128;
    const int col0 = blockIdx.y * 128;

    const int c0r = tid >> 2;
    const int c0k = (tid & 3) * 8;

    f32x4 acc[4][4] = {};

    const int rA = lane & 15;
    const int kb = (lane >> 4) * 8;

    for (int t = 0; t < 16; ++t) {
        const int k0 = t * 32;
        gload16(Xb + (size_t)(row0 + c0r) * FDIM + k0 + c0k,        &As[tid * 8]);
        gload16(Xb + (size_t)(row0 + 64 + c0r) * FDIM + k0 + c0k,   &As[2048 + tid * 8]);
        gload16(Wb + (size_t)(col0 + c0r) * FDIM + k0 + c0k,        &Bs[tid * 8]);
        gload16(Wb + (size_t)(col0 + 64 + c0r) * FDIM + k0 + c0k,   &Bs[2048 + tid * 8]);
        __syncthreads();

        bf16x8 af[4], bfr[4];
        #pragma unroll
        for (int mi = 0; mi < 4; ++mi)
            af[mi] = *(const bf16x8*)&As[(wr + mi * 16 + rA) * 32 + kb];
        #pragma unroll
        for (int ni = 0; ni < 4; ++ni)
            bfr[ni] = *(const bf16x8*)&Bs[(wc + ni * 16 + rA) * 32 + kb];

        #pragma unroll
        for (int mi = 0; mi < 4; ++mi)
            #pragma unroll
            for (int ni = 0; ni < 4; ++ni)
                acc[mi][ni] = __builtin_amdgcn_mfma_f32_16x16x32_bf16(
                    af[mi], bfr[ni], acc[mi][ni], 0, 0, 0);
        __syncthreads();
    }

    // C/D map: col = lane&15, row = (lane>>4)*4 + reg
    const int colb = col0 + wc + (lane & 15);
    const int rowb = row0 + wr + (lane >> 4) * 4;
    #pragma unroll
    for (int ni = 0; ni < 4; ++ni) {
        const int col = colb + ni * 16;
        const float bv = bias[col];
        #pragma unroll
        for (int mi = 0; mi < 4; ++mi) {
            const int row = rowb + mi * 16;
            #pragma unroll
            for (int j = 0; j < 4; ++j)
                L[(size_t)(row + j) * GE + col] = acc[mi][ni][j] + bv;
        }
    }
}

// ---------------- per-(n,g) epilogue ----------------
// 2048 blocks x 4 waves; each wave owns 4 rows (same g per block).
// L aliases the cb out region (read then overwritten by the owning wave).
__global__ __launch_bounds__(256) void vq_rows_k(
    float* __restrict__ Lcb,                 // logits in, cb out (same region)
    const float* __restrict__ gumbel,
    const float* __restrict__ entries,
    float* __restrict__ out,                 // d_out base (quantized at 0)
    float* __restrict__ acc_slots,           // nslots x 1280 floats in ws
    int nslots)
{
    __shared__ float redH[320], redS[320];

    const int tid  = threadIdx.x;
    const int lane = tid & 63;
    const int w    = blockIdx.x * 4 + (tid >> 6);   // 0..8191
    const int g    = w >> 12;                        // uniform per block
    const int nb   = w & 4095;

    for (int e = tid; e < 320; e += 256) { redH[e] = 0.f; redS[e] = 0.f; }

    float racc[5] = {0.f, 0.f, 0.f, 0.f, 0.f};
    float hacc[5] = {0.f, 0.f, 0.f, 0.f, 0.f};

    float l[5], gu[5], l2[5], gu2[5];
    {
        const float* lrow = Lcb + (size_t)nb * GE + g * EDIM;
        const float* grow = gumbel + ((size_t)nb * 2 + g) * EDIM;
        #pragma unroll
        for (int j = 0; j < 5; ++j) {
            l[j]  = lrow[lane + j * 64];
            gu[j] = grow[lane + j * 64];
        }
    }

    #pragma unroll 1
    for (int i = 0; i < 4; ++i) {
        const int n = nb + (i << 12);
        if (i < 3) {
            const int n2 = nb + ((i + 1) << 12);
            const float* lrow2 = Lcb + (size_t)n2 * GE + g * EDIM;
            const float* grow2 = gumbel + ((size_t)n2 * 2 + g) * EDIM;
            #pragma unroll
            for (int j = 0; j < 5; ++j) {
                l2[j]  = lrow2[lane + j * 64];
                gu2[j] = grow2[lane + j * 64];
            }
        }

        float t[5];
        #pragma unroll
        for (int j = 0; j < 5; ++j)
            t[j] = (l[j] + gu[j]) * 0.5f;   // (logits+gumbel)/TAU, TAU=2

        // local argmax (first-index tie-break)
        float hv = l[0]; int hi = lane;
        float gv = t[0]; int gi = lane;
        #pragma unroll
        for (int j = 1; j < 5; ++j) {
            const int e = lane + j * 64;
            if (l[j] > hv) { hv = l[j]; hi = e; }
            if (t[j] > gv) { gv = t[j]; gi = e; }
        }
        #pragma unroll
        for (int off = 32; off > 0; off >>= 1) {
            float ov = __shfl_xor(hv, off); int oi = __shfl_xor(hi, off);
            if (ov > hv || (ov == hv && oi < hi)) { hv = ov; hi = oi; }
            float ov2 = __shfl_xor(gv, off); int oi2 = __shfl_xor(gi, off);
            if (ov2 > gv || (ov2 == gv && oi2 < gi)) { gv = ov2; gi = oi2; }
        }

        // softmax exps + sums
        float eh[5], eg[5];
        float sh = 0.f, sg = 0.f;
        #pragma unroll
        for (int j = 0; j < 5; ++j) {
            eh[j] = expf(l[j] - hv);
            eg[j] = expf(t[j] - gv);
            sh += eh[j]; sg += eg[j];
        }
        #pragma unroll
        for (int off = 32; off > 0; off >>= 1) {
            sh += __shfl_xor(sh, off);
            sg += __shfl_xor(sg, off);
        }
        const float ish = 1.0f / sh;
        const float isg = 1.0f / sg;

        // y_soft at the gumbel argmax: gi is wave-uniform -> select + 1 shfl
        const int gs = gi >> 6;   // slot (uniform)
        float esel = eg[0];
        esel = (gs == 1) ? eg[1] : esel;
        esel = (gs == 2) ? eg[2] : esel;
        esel = (gs == 3) ? eg[3] : esel;
        esel = (gs == 4) ? eg[4] : esel;
        const float a_part = __shfl(esel, gi & 63) * isg;
        const float yv = (1.0f - a_part) + a_part;   // straight-through value

        // accumulate soft probs + hard counts
        #pragma unroll
        for (int j = 0; j < 5; ++j) {
            const int e = lane + j * 64;
            racc[j] += eh[j] * ish;
            if (e == hi) hacc[j] += 1.0f;
        }

        // cb write (overwrites logits slice in place)
        float* lrow = Lcb + (size_t)n * GE + g * EDIM;
        #pragma unroll
        for (int j = 0; j < 5; ++j) {
            const int e = lane + j * 64;
            lrow[e] = (e == gi) ? yv : 0.0f;
        }

        // quantized write: yv * entries[g, gi, :]
        const float* ent = entries + ((size_t)(g * EDIM + gi)) * DDIM;
        float* qrow = out + (size_t)n * 768 + g * DDIM;
        #pragma unroll
        for (int jj = 0; jj < 6; ++jj) {
            const int d = lane + jj * 64;
            qrow[d] = yv * ent[d];
        }

        #pragma unroll
        for (int j = 0; j < 5; ++j) { l[j] = l2[j]; gu[j] = gu2[j]; }
    }

    // block-level LDS reduction, then one atomic per entry into our slot
    __syncthreads();
    #pragma unroll
    for (int j = 0; j < 5; ++j) {
        atomicAdd(&redH[lane + j * 64], hacc[j]);
        atomicAdd(&redS[lane + j * 64], racc[j]);
    }
    __syncthreads();
    float* slot = acc_slots + (size_t)(blockIdx.x & (nslots - 1)) * 1280;
    for (int e = tid; e < 320; e += 256) {
        atomicAdd(&slot[g * EDIM + e], redH[e]);
        atomicAdd(&slot[640 + g * EDIM + e], redS[e]);
    }
}

// ---------------- perplexities ----------------
__global__ void vq_final_k(const float* __restrict__ acc_slots, int nslots,
                           float* __restrict__ out)
{
    const int lane = threadIdx.x & 63;
    float code = 0.f, prob = 0.f;
    for (int g = 0; g < 2; ++g) {
        float shh = 0.f, sss = 0.f;
        #pragma unroll
        for (int j = 0; j < 5; ++j) {
            const int e = g * EDIM + lane + j * 64;
            float ph = 0.f, ps = 0.f;
            for (int s = 0; s < nslots; ++s) {
                ph += acc_slots[(size_t)s * 1280 + e];
                ps += acc_slots[(size_t)s * 1280 + 640 + e];
            }
            ph *= (1.0f / 16384.0f);
            ps *= (1.0f / 16384.0f);
            shh += ph * logf(ph + 1e-7f);
            sss += ps * logf(ps + 1e-7f);
        }
        #pragma unroll
        for (int off = 32; off > 0; off >>= 1) {
            shh += __shfl_xor(shh, off);
            sss += __shfl_xor(sss, off);
        }
        code += expf(-shh);
        prob += expf(-sss);
    }
    if (threadIdx.x == 0) {
        out[SCAL_OFF + 0] = code;
        out[SCAL_OFF + 1] = prob;
    }
}

extern "C" void kernel_launch(void* const* d_in, const int* in_sizes, int n_in,
                              void* d_out, int out_size, void* d_ws, size_t ws_size,
                              hipStream_t stream) {
    const float* x       = (const float*)d_in[0];
    const float* proj_w  = (const float*)d_in[1];
    const float* proj_b  = (const float*)d_in[2];
    const float* entries = (const float*)d_in[3];
    const float* gumbel  = (const float*)d_in[4];
    float* out = (float*)d_out;
    float* acc = (float*)d_ws;
    float* logits = out + CB_OFF;                  // logits staged in cb region
    ushort_t* Xb = (ushort_t*)(out + XB_OFF);      // bf16 X in quantized region
    ushort_t* Wb = (ushort_t*)(out + WB_OFF);      // bf16 W after it

    // 32-way privatized accumulator slots if ws allows (32*1280*4B = 160 KB)
    const int nslots = (ws_size >= (size_t)32 * 1280 * 4) ? 32 : 1;
    const int nz = nslots * 1280;

    hipLaunchKernelGGL(vq_init_k, dim3((nz + 255) / 256), dim3(256), 0, stream,
                       acc, nz);
    hipLaunchKernelGGL(convert_bf16_k, dim3(4256), dim3(256), 0, stream,
                       x, proj_w, Xb, Wb);
    hipLaunchKernelGGL(gemm_mfma_k, dim3(NROWS / 128, GE / 128), dim3(256), 0, stream,
                       Xb, Wb, proj_b, logits);
    hipLaunchKernelGGL(vq_rows_k, dim3(2048), dim3(256), 0, stream,
                       logits, gumbel, entries, out, acc, nslots);
    hipLaunchKernelGGL(vq_final_k, dim3(1), dim3(64), 0, stream,
                       acc, nslots, out);
}

// Round 5
// 103.067 us; speedup vs baseline: 1.7209x; 1.7209x over previous
//
#include <hip/hip_runtime.h>
#include <hip/hip_bf16.h>

typedef unsigned short ushort_t;
typedef __attribute__((ext_vector_type(8))) short bf16x8;
typedef __attribute__((ext_vector_type(4))) float f32x4;

// Problem constants
#define NROWS 16384          // B*T
#define FDIM  512            // K
#define GE    640            // G*E
#define EDIM  320
#define DDIM  384
#define CB_OFF 12582912      // 16384*768
#define SCAL_OFF 23068672    // CB_OFF + 16384*640
// bf16 staging inside out[quantized region] (free until vq_rows)
#define XB_OFF 0             // 8388608 bf16 = 4194304 floats
#define WB_OFF 4194304       // floats; 327680 bf16 = 163840 floats

// ---------------- init accumulators ----------------
__global__ void vq_init_k(float* acc, int n) {
    int i = blockIdx.x * 256 + threadIdx.x;
    if (i < n) acc[i] = 0.0f;
}

// ---------------- fp32 -> bf16 convert (RNE) ----------------
static __device__ __forceinline__ unsigned f2bf(float f) {
    unsigned u = __float_as_uint(f);
    return (u + 0x7FFFu + ((u >> 16) & 1u)) >> 16;
}

__global__ __launch_bounds__(256) void convert_bf16_k(
    const float* __restrict__ X, const float* __restrict__ W,
    ushort_t* __restrict__ Xb, ushort_t* __restrict__ Wb)
{
    const size_t i = (size_t)blockIdx.x * 256 + threadIdx.x;
    const float4* src;
    ushort_t* dst;
    if (i < 1048576) {                    // X: 8388608 elems / 8
        src = (const float4*)X + i * 2;
        dst = Xb + i * 8;
    } else {                              // W: 327680 elems / 8
        const size_t j = i - 1048576;
        src = (const float4*)W + j * 2;
        dst = Wb + j * 8;
    }
    const float4 v0 = src[0], v1 = src[1];
    uint4 o;
    o.x = f2bf(v0.x) | (f2bf(v0.y) << 16);
    o.y = f2bf(v0.z) | (f2bf(v0.w) << 16);
    o.z = f2bf(v1.x) | (f2bf(v1.y) << 16);
    o.w = f2bf(v1.z) | (f2bf(v1.w) << 16);
    *(uint4*)dst = o;
}

// ---------------- async global->LDS helper ----------------
static __device__ __forceinline__ void gload16(const void* g, void* l) {
    __builtin_amdgcn_global_load_lds(
        (const __attribute__((address_space(1))) unsigned int*)g,
        (__attribute__((address_space(3))) unsigned int*)l, 16, 0, 0);
}

// ---------------- MFMA GEMM: L = Xb @ Wb^T + b ----------------
__global__ __launch_bounds__(256) void gemm_mfma_k(
    const ushort_t* __restrict__ Xb, const ushort_t* __restrict__ Wb,
    const float* __restrict__ bias, float* __restrict__ L)
{
    __shared__ __align__(16) ushort_t As[128 * 32];   // [row][k], 64B/row
    __shared__ __align__(16) ushort_t Bs[128 * 32];

    const int tid  = threadIdx.x;
    const int lane = tid & 63;
    const int wv   = tid >> 6;          // 0..3
    const int wr   = (wv >> 1) * 64;
    const int wc   = (wv & 1) * 64;
    const int row0 = blockIdx.x * 128;
    const int col0 = blockIdx.y * 128;

    const int c0r = tid >> 2;
    const int c0k = (tid & 3) * 8;

    f32x4 acc[4][4] = {};

    const int rA = lane & 15;
    const int kb = (lane >> 4) * 8;

    for (int t = 0; t < 16; ++t) {
        const int k0 = t * 32;
        gload16(Xb + (size_t)(row0 + c0r) * FDIM + k0 + c0k,        &As[tid * 8]);
        gload16(Xb + (size_t)(row0 + 64 + c0r) * FDIM + k0 + c0k,   &As[2048 + tid * 8]);
        gload16(Wb + (size_t)(col0 + c0r) * FDIM + k0 + c0k,        &Bs[tid * 8]);
        gload16(Wb + (size_t)(col0 + 64 + c0r) * FDIM + k0 + c0k,   &Bs[2048 + tid * 8]);
        __syncthreads();

        bf16x8 af[4], bfr[4];
        #pragma unroll
        for (int mi = 0; mi < 4; ++mi)
            af[mi] = *(const bf16x8*)&As[(wr + mi * 16 + rA) * 32 + kb];
        #pragma unroll
        for (int ni = 0; ni < 4; ++ni)
            bfr[ni] = *(const bf16x8*)&Bs[(wc + ni * 16 + rA) * 32 + kb];

        #pragma unroll
        for (int mi = 0; mi < 4; ++mi)
            #pragma unroll
            for (int ni = 0; ni < 4; ++ni)
                acc[mi][ni] = __builtin_amdgcn_mfma_f32_16x16x32_bf16(
                    af[mi], bfr[ni], acc[mi][ni], 0, 0, 0);
        __syncthreads();
    }

    // C/D map: col = lane&15, row = (lane>>4)*4 + reg
    const int colb = col0 + wc + (lane & 15);
    const int rowb = row0 + wr + (lane >> 4) * 4;
    #pragma unroll
    for (int ni = 0; ni < 4; ++ni) {
        const int col = colb + ni * 16;
        const float bv = bias[col];
        #pragma unroll
        for (int mi = 0; mi < 4; ++mi) {
            const int row = rowb + mi * 16;
            #pragma unroll
            for (int j = 0; j < 4; ++j)
                L[(size_t)(row + j) * GE + col] = acc[mi][ni][j] + bv;
        }
    }
}

// ---------------- per-(n,g) epilogue ----------------
// 2048 blocks x 4 waves; each wave owns 4 rows (same g per block).
// L aliases the cb out region (read then overwritten by the owning wave).
__global__ __launch_bounds__(256) void vq_rows_k(
    float* __restrict__ Lcb,                 // logits in, cb out (same region)
    const float* __restrict__ gumbel,
    const float* __restrict__ entries,
    float* __restrict__ out,                 // d_out base (quantized at 0)
    float* __restrict__ acc_slots,           // nslots x 1280 floats in ws
    int nslots)
{
    __shared__ float redH[320], redS[320];

    const int tid  = threadIdx.x;
    const int lane = tid & 63;
    const int w    = blockIdx.x * 4 + (tid >> 6);   // 0..8191
    const int g    = w >> 12;                        // uniform per block
    const int nb   = w & 4095;

    for (int e = tid; e < 320; e += 256) { redH[e] = 0.f; redS[e] = 0.f; }

    float racc[5] = {0.f, 0.f, 0.f, 0.f, 0.f};
    float hacc[5] = {0.f, 0.f, 0.f, 0.f, 0.f};

    float l[5], gu[5], l2[5], gu2[5];
    {
        const float* lrow = Lcb + (size_t)nb * GE + g * EDIM;
        const float* grow = gumbel + ((size_t)nb * 2 + g) * EDIM;
        #pragma unroll
        for (int j = 0; j < 5; ++j) {
            l[j]  = lrow[lane + j * 64];
            gu[j] = grow[lane + j * 64];
        }
    }

    #pragma unroll 1
    for (int i = 0; i < 4; ++i) {
        const int n = nb + (i << 12);
        if (i < 3) {
            const int n2 = nb + ((i + 1) << 12);
            const float* lrow2 = Lcb + (size_t)n2 * GE + g * EDIM;
            const float* grow2 = gumbel + ((size_t)n2 * 2 + g) * EDIM;
            #pragma unroll
            for (int j = 0; j < 5; ++j) {
                l2[j]  = lrow2[lane + j * 64];
                gu2[j] = grow2[lane + j * 64];
            }
        }

        float t[5];
        #pragma unroll
        for (int j = 0; j < 5; ++j)
            t[j] = (l[j] + gu[j]) * 0.5f;   // (logits+gumbel)/TAU, TAU=2

        // local argmax (first-index tie-break)
        float hv = l[0]; int hi = lane;
        float gv = t[0]; int gi = lane;
        #pragma unroll
        for (int j = 1; j < 5; ++j) {
            const int e = lane + j * 64;
            if (l[j] > hv) { hv = l[j]; hi = e; }
            if (t[j] > gv) { gv = t[j]; gi = e; }
        }
        #pragma unroll
        for (int off = 32; off > 0; off >>= 1) {
            float ov = __shfl_xor(hv, off); int oi = __shfl_xor(hi, off);
            if (ov > hv || (ov == hv && oi < hi)) { hv = ov; hi = oi; }
            float ov2 = __shfl_xor(gv, off); int oi2 = __shfl_xor(gi, off);
            if (ov2 > gv || (ov2 == gv && oi2 < gi)) { gv = ov2; gi = oi2; }
        }

        // softmax exps + sums (native v_exp: indices unaffected, soft err ~1e-6)
        float eh[5], eg[5];
        float sh = 0.f, sg = 0.f;
        #pragma unroll
        for (int j = 0; j < 5; ++j) {
            eh[j] = __expf(l[j] - hv);
            eg[j] = __expf(t[j] - gv);
            sh += eh[j]; sg += eg[j];
        }
        #pragma unroll
        for (int off = 32; off > 0; off >>= 1) {
            sh += __shfl_xor(sh, off);
            sg += __shfl_xor(sg, off);
        }
        const float ish = 1.0f / sh;
        const float isg = 1.0f / sg;

        // y_soft at the gumbel argmax: gi is wave-uniform -> select + 1 shfl
        const int gs = gi >> 6;   // slot (uniform)
        float esel = eg[0];
        esel = (gs == 1) ? eg[1] : esel;
        esel = (gs == 2) ? eg[2] : esel;
        esel = (gs == 3) ? eg[3] : esel;
        esel = (gs == 4) ? eg[4] : esel;
        const float a_part = __shfl(esel, gi & 63) * isg;
        const float yv = (1.0f - a_part) + a_part;   // straight-through value

        // accumulate soft probs + hard counts
        #pragma unroll
        for (int j = 0; j < 5; ++j) {
            const int e = lane + j * 64;
            racc[j] += eh[j] * ish;
            if (e == hi) hacc[j] += 1.0f;
        }

        // cb write (overwrites logits slice in place)
        float* lrow = Lcb + (size_t)n * GE + g * EDIM;
        #pragma unroll
        for (int j = 0; j < 5; ++j) {
            const int e = lane + j * 64;
            lrow[e] = (e == gi) ? yv : 0.0f;
        }

        // quantized write: yv * entries[g, gi, :]
        const float* ent = entries + ((size_t)(g * EDIM + gi)) * DDIM;
        float* qrow = out + (size_t)n * 768 + g * DDIM;
        #pragma unroll
        for (int jj = 0; jj < 6; ++jj) {
            const int d = lane + jj * 64;
            qrow[d] = yv * ent[d];
        }

        #pragma unroll
        for (int j = 0; j < 5; ++j) { l[j] = l2[j]; gu[j] = gu2[j]; }
    }

    // block-level LDS reduction, then one atomic per entry into our slot
    __syncthreads();
    #pragma unroll
    for (int j = 0; j < 5; ++j) {
        atomicAdd(&redH[lane + j * 64], hacc[j]);
        atomicAdd(&redS[lane + j * 64], racc[j]);
    }
    __syncthreads();
    float* slot = acc_slots + (size_t)(blockIdx.x & (nslots - 1)) * 1280;
    for (int e = tid; e < 320; e += 256) {
        atomicAdd(&slot[g * EDIM + e], redH[e]);
        atomicAdd(&slot[640 + g * EDIM + e], redS[e]);
    }
}

// ---------------- parallel slot reduction: 1280 threads ----------------
__global__ __launch_bounds__(256) void reduce_slots_k(
    const float* __restrict__ acc_slots, int nslots, float* __restrict__ red)
{
    const int idx = blockIdx.x * 256 + threadIdx.x;   // 0..1279
    if (idx >= 1280) return;
    float s = 0.f;
    for (int k = 0; k < nslots; ++k)
        s += acc_slots[(size_t)k * 1280 + idx];
    red[idx] = s;
}

// ---------------- perplexities ----------------
__global__ void vq_final_k(const float* __restrict__ red,
                           float* __restrict__ out)
{
    const int lane = threadIdx.x & 63;
    float code = 0.f, prob = 0.f;
    for (int g = 0; g < 2; ++g) {
        float shh = 0.f, sss = 0.f;
        #pragma unroll
        for (int j = 0; j < 5; ++j) {
            const int e = g * EDIM + lane + j * 64;
            const float ph = red[e] * (1.0f / 16384.0f);
            const float ps = red[640 + e] * (1.0f / 16384.0f);
            shh += ph * __logf(ph + 1e-7f);
            sss += ps * __logf(ps + 1e-7f);
        }
        #pragma unroll
        for (int off = 32; off > 0; off >>= 1) {
            shh += __shfl_xor(shh, off);
            sss += __shfl_xor(sss, off);
        }
        code += __expf(-shh);
        prob += __expf(-sss);
    }
    if (threadIdx.x == 0) {
        out[SCAL_OFF + 0] = code;
        out[SCAL_OFF + 1] = prob;
    }
}

extern "C" void kernel_launch(void* const* d_in, const int* in_sizes, int n_in,
                              void* d_out, int out_size, void* d_ws, size_t ws_size,
                              hipStream_t stream) {
    const float* x       = (const float*)d_in[0];
    const float* proj_w  = (const float*)d_in[1];
    const float* proj_b  = (const float*)d_in[2];
    const float* entries = (const float*)d_in[3];
    const float* gumbel  = (const float*)d_in[4];
    float* out = (float*)d_out;
    float* acc = (float*)d_ws;
    float* logits = out + CB_OFF;                  // logits staged in cb region
    ushort_t* Xb = (ushort_t*)(out + XB_OFF);      // bf16 X in quantized region
    ushort_t* Wb = (ushort_t*)(out + WB_OFF);      // bf16 W after it

    // 16 privatized slots + 1 reduced buffer: (16+1)*1280*4 = 87 KB
    const int nslots = (ws_size >= (size_t)17 * 1280 * 4) ? 16 : 1;
    float* red = acc + (size_t)nslots * 1280;
    const int nz = nslots * 1280;

    hipLaunchKernelGGL(vq_init_k, dim3((nz + 255) / 256), dim3(256), 0, stream,
                       acc, nz);
    hipLaunchKernelGGL(convert_bf16_k, dim3(4256), dim3(256), 0, stream,
                       x, proj_w, Xb, Wb);
    hipLaunchKernelGGL(gemm_mfma_k, dim3(NROWS / 128, GE / 128), dim3(256), 0, stream,
                       Xb, Wb, proj_b, logits);
    hipLaunchKernelGGL(vq_rows_k, dim3(2048), dim3(256), 0, stream,
                       logits, gumbel, entries, out, acc, nslots);
    hipLaunchKernelGGL(reduce_slots_k, dim3(5), dim3(256), 0, stream,
                       acc, nslots, red);
    hipLaunchKernelGGL(vq_final_k, dim3(1), dim3(64), 0, stream,
                       red, out);
}